// Round 4
// baseline (232.227 us; speedup 1.0000x reference)
//
#include <hip/hip_runtime.h>
#include <math.h>

#define TB 2048
#define TK 128
#define TD 512
#define DSPLIT 32
#define DLEN 16            // TD / DSPLIT
#define BROWS 128
#define NBB (TB / BROWS)   // 16

// ws layout: [0, 1MB) dist_sq accumulator [b][k]; [1MB, 1MB+512) det_sf accum [k]

// ---------------------------------------------------------------------------
// dist kernel: block = 128 rows x 128 k x 16 d slice. Thread = 8 rows x 8 k.
// Params (u = rsqrt(|D|+eps), cu = c*u) computed into LDS on the fly.
// Partial dist_sq accumulated into global f32 accumulator via atomics.
// rb==0 blocks (one per d-slice) also accumulate the log-det partial.
// ---------------------------------------------------------------------------
__global__ __launch_bounds__(256, 2) void dist_kernel(
        const float* __restrict__ x, const float* __restrict__ C,
        const float* __restrict__ Dm, float* __restrict__ dist_acc,
        float* __restrict__ det_acc) {
    __shared__ float sa[DLEN][TK];     // 8 KB
    __shared__ float sb[DLEN][TK];     // 8 KB
    __shared__ float xs[DLEN][BROWS];  // 8 KB, transposed x tile

    const int tid = threadIdx.x;
    const int rb = blockIdx.x / DSPLIT;
    const int ds = blockIdx.x % DSPLIT;
    const int b0 = rb * BROWS;
    const int d0 = ds * DLEN;

    // ---- stage params: thread-pair covers one k row (8 d's each) ----
    {
        const int kk = tid >> 1;             // 0..127
        const int dh = (tid & 1) * 8;        // 0 or 8
        const float4* Dg = reinterpret_cast<const float4*>(Dm + (size_t)kk * TD + d0 + dh);
        const float4* Cg = reinterpret_cast<const float4*>(C  + (size_t)kk * TD + d0 + dh);
        float lsum = 0.f;
        #pragma unroll
        for (int j = 0; j < 2; ++j) {
            float4 dv = Dg[j];
            float4 cv = Cg[j];
            int db = dh + j * 4;
            float da, u;
            da = fabsf(dv.x) + 1e-8f; u = rsqrtf(da); sa[db+0][kk] = u; sb[db+0][kk] = cv.x * u; lsum += logf(da);
            da = fabsf(dv.y) + 1e-8f; u = rsqrtf(da); sa[db+1][kk] = u; sb[db+1][kk] = cv.y * u; lsum += logf(da);
            da = fabsf(dv.z) + 1e-8f; u = rsqrtf(da); sa[db+2][kk] = u; sb[db+2][kk] = cv.z * u; lsum += logf(da);
            da = fabsf(dv.w) + 1e-8f; u = rsqrtf(da); sa[db+3][kk] = u; sb[db+3][kk] = cv.w * u; lsum += logf(da);
        }
        if (rb == 0) {
            lsum += __shfl_xor(lsum, 1, 64);
            if ((tid & 1) == 0) atomicAdd(&det_acc[kk], -0.5f * lsum);
        }
    }

    // ---- stage x tile transposed: xs[d][row] ----
    {
        #pragma unroll
        for (int i = 0; i < 2; ++i) {
            int idx = tid + i * 256;        // 0..511
            int row = idx >> 2;             // 0..127
            int dq  = (idx & 3) * 4;        // 0,4,8,12
            float4 v = *reinterpret_cast<const float4*>(
                x + (size_t)(b0 + row) * TD + d0 + dq);
            xs[dq + 0][row] = v.x;
            xs[dq + 1][row] = v.y;
            xs[dq + 2][row] = v.z;
            xs[dq + 3][row] = v.w;
        }
    }
    __syncthreads();

    const int k0 = (tid & 15) * 8;
    const int r0 = (tid >> 4) * 8;

    float acc[8][8];
    #pragma unroll
    for (int r = 0; r < 8; ++r)
        #pragma unroll
        for (int k = 0; k < 8; ++k) acc[r][k] = 0.f;

    #pragma unroll 4
    for (int d = 0; d < DLEN; ++d) {
        float4 ua = *reinterpret_cast<const float4*>(&sa[d][k0]);
        float4 ub = *reinterpret_cast<const float4*>(&sa[d][k0 + 4]);
        float4 ca = *reinterpret_cast<const float4*>(&sb[d][k0]);
        float4 cb = *reinterpret_cast<const float4*>(&sb[d][k0 + 4]);
        float4 xa = *reinterpret_cast<const float4*>(&xs[d][r0]);
        float4 xb = *reinterpret_cast<const float4*>(&xs[d][r0 + 4]);
        float uu[8] = {ua.x, ua.y, ua.z, ua.w, ub.x, ub.y, ub.z, ub.w};
        float cc[8] = {ca.x, ca.y, ca.z, ca.w, cb.x, cb.y, cb.z, cb.w};
        float xx[8] = {xa.x, xa.y, xa.z, xa.w, xb.x, xb.y, xb.z, xb.w};
        #pragma unroll
        for (int r = 0; r < 8; ++r) {
            #pragma unroll
            for (int k = 0; k < 8; ++k) {
                float t = fmaf(xx[r], uu[k], -cc[k]);
                acc[r][k] = fmaf(t, t, acc[r][k]);
            }
        }
    }

    #pragma unroll
    for (int r = 0; r < 8; ++r) {
        #pragma unroll
        for (int k = 0; k < 8; ++k) {
            atomicAdd(&dist_acc[(size_t)(b0 + r0 + r) * TK + k0 + k], acc[r][k]);
        }
    }
}

// ---------------------------------------------------------------------------
// Finish: s[k] = det_sf[k] - 0.5*dist_sq; log-softmax over k; argmax + dist.
// 4 waves/block, 1 row/wave, lane handles k = 2*lane, 2*lane+1.
// ---------------------------------------------------------------------------
__global__ __launch_bounds__(256) void finish_kernel(
        const float* __restrict__ dist_acc, const float* __restrict__ det_acc,
        float* __restrict__ out) {
    const int lane = threadIdx.x & 63;
    const int wv = threadIdx.x >> 6;
    const int b = blockIdx.x * 4 + wv;
    const int k0 = lane * 2;

    float2 dd = *reinterpret_cast<const float2*>(&dist_acc[(size_t)b * TK + k0]);
    float2 dt = *reinterpret_cast<const float2*>(&det_acc[k0]);
    float s0 = fmaf(-0.5f, dd.x, dt.x);
    float s1 = fmaf(-0.5f, dd.y, dt.y);

    float m = fmaxf(s0, s1);
    #pragma unroll
    for (int msk = 32; msk >= 1; msk >>= 1) m = fmaxf(m, __shfl_xor(m, msk, 64));
    float p0 = expf(s0 - m), p1 = expf(s1 - m);
    float ps = p0 + p1;
    #pragma unroll
    for (int msk = 32; msk >= 1; msk >>= 1) ps += __shfl_xor(ps, msk, 64);
    float lse = logf(ps) + m;

    const float LOGC = -18.420680743952367f;  // ln(1e-8)
    float2 o;
    o.x = fmaxf(s0 - lse, LOGC);
    o.y = fmaxf(s1 - lse, LOGC);
    *reinterpret_cast<float2*>(&out[(size_t)b * TK + k0]) = o;

    // Argmax over s (first index on ties), carrying dist_sq.
    float bv; int bi; float bd;
    if (s1 > s0) { bv = s1; bi = k0 + 1; bd = dd.y; }
    else         { bv = s0; bi = k0;     bd = dd.x; }
    #pragma unroll
    for (int msk = 32; msk >= 1; msk >>= 1) {
        float ov = __shfl_xor(bv, msk, 64);
        int   oi = __shfl_xor(bi, msk, 64);
        float od = __shfl_xor(bd, msk, 64);
        if (ov > bv || (ov == bv && oi < bi)) { bv = ov; bi = oi; bd = od; }
    }
    if (lane == 0) out[(size_t)TB * TK + b] = sqrtf(bd);
}

// ---------------------------------------------------------------------------
extern "C" void kernel_launch(void* const* d_in, const int* in_sizes, int n_in,
                              void* d_out, int out_size, void* d_ws, size_t ws_size,
                              hipStream_t stream) {
    const float* x  = (const float*)d_in[0];
    const float* C  = (const float*)d_in[1];
    const float* Dm = (const float*)d_in[2];
    float* out = (float*)d_out;

    float* dist_acc = (float*)d_ws;                              // 1 MB
    float* det_acc  = (float*)((char*)d_ws + (1ull << 20));      // 512 B

    hipMemsetAsync(d_ws, 0, (1ull << 20) + 512, stream);

    dist_kernel<<<NBB * DSPLIT, 256, 0, stream>>>(x, C, Dm, dist_acc, det_acc);
    finish_kernel<<<TB / 4, 256, 0, stream>>>(dist_acc, det_acc, out);
}

// Round 5
// 30.223 us; speedup vs baseline: 7.6839x; 7.6839x over previous
//
#include <hip/hip_runtime.h>
#include <math.h>

#define TB 2048
#define TK 128
#define TD 512
#define DSPLIT 16
#define DLEN 32            // TD / DSPLIT
#define BROWS 64
#define NRB (TB / BROWS)   // 32

// ws layout: [0, 16MB) part[ds][b][k] ; [16MB, +8KB) logdet_part[ds][k]

// ---------------------------------------------------------------------------
// dist kernel: block = 64 rows x 128 k x 32 d slice; 128 threads (2 waves).
// Thread tile = 8 rows x 8 k. One-shot LDS staging (params computed in-block,
// transposed [d][k]; x tile linear), one barrier, then pure FMA.
// ---------------------------------------------------------------------------
__global__ __launch_bounds__(128) void dist_kernel(
        const float* __restrict__ x, const float* __restrict__ C,
        const float* __restrict__ Dm, float* __restrict__ part,
        float* __restrict__ logdet_part) {
    __shared__ float sa[DLEN][TK];    // 16 KB : u = rsqrt(|D|+eps)
    __shared__ float sb[DLEN][TK];    // 16 KB : c*u
    __shared__ float xs[BROWS][DLEN]; //  8 KB

    const int tid = threadIdx.x;
    const int rb = blockIdx.x / DSPLIT;
    const int ds = blockIdx.x % DSPLIT;
    const int b0 = rb * BROWS;
    const int d0 = ds * DLEN;

    // ---- stage x tile: 64 rows x 32 d = 512 float4, 4 per thread ----
    #pragma unroll
    for (int i = 0; i < 4; ++i) {
        int f = i * 128 + tid;        // 0..511
        int row = f >> 3;             // 0..63
        int j = f & 7;                // f4 index within row slice
        float4 v = *reinterpret_cast<const float4*>(
            &x[(size_t)(b0 + row) * TD + d0 + j * 4]);
        *reinterpret_cast<float4*>(&xs[row][j * 4]) = v;
    }

    // ---- stage params: 128 k x 8 f4 = 1024 f4, 8 per thread (coalesced) ----
    #pragma unroll
    for (int i = 0; i < 8; ++i) {
        int f = i * 128 + tid;        // 0..1023
        int k = f >> 3;               // 0..127
        int j = f & 7;
        float4 dv = *reinterpret_cast<const float4*>(&Dm[(size_t)k * TD + d0 + j * 4]);
        float4 cv = *reinterpret_cast<const float4*>(&C[(size_t)k * TD + d0 + j * 4]);
        float da0 = fabsf(dv.x) + 1e-8f, u0 = rsqrtf(da0);
        float da1 = fabsf(dv.y) + 1e-8f, u1 = rsqrtf(da1);
        float da2 = fabsf(dv.z) + 1e-8f, u2 = rsqrtf(da2);
        float da3 = fabsf(dv.w) + 1e-8f, u3 = rsqrtf(da3);
        int db = j * 4;
        sa[db + 0][k] = u0; sb[db + 0][k] = cv.x * u0;
        sa[db + 1][k] = u1; sb[db + 1][k] = cv.y * u1;
        sa[db + 2][k] = u2; sb[db + 2][k] = cv.z * u2;
        sa[db + 3][k] = u3; sb[db + 3][k] = cv.w * u3;
        if (rb == 0) {
            // log-det partial for this slice: reduce over the 8 threads (j=0..7)
            // that share k (they are lanes tid&7 within one 8-lane group).
            float ls = logf(da0) + logf(da1) + logf(da2) + logf(da3);
            ls += __shfl_xor(ls, 1, 64);
            ls += __shfl_xor(ls, 2, 64);
            ls += __shfl_xor(ls, 4, 64);
            if ((tid & 7) == 0) logdet_part[ds * TK + k] = -0.5f * ls;
        }
    }
    __syncthreads();

    const int k0 = (tid & 15) * 8;
    const int r0 = (tid >> 4) * 8;

    float acc[8][8];
    #pragma unroll
    for (int r = 0; r < 8; ++r)
        #pragma unroll
        for (int k = 0; k < 8; ++k) acc[r][k] = 0.f;

    #pragma unroll 2
    for (int d4 = 0; d4 < DLEN / 4; ++d4) {
        float4 xv[8];
        #pragma unroll
        for (int r = 0; r < 8; ++r)
            xv[r] = *reinterpret_cast<const float4*>(&xs[r0 + r][d4 * 4]);
        #pragma unroll
        for (int dd = 0; dd < 4; ++dd) {
            int d = d4 * 4 + dd;
            float4 ua = *reinterpret_cast<const float4*>(&sa[d][k0]);
            float4 ub = *reinterpret_cast<const float4*>(&sa[d][k0 + 4]);
            float4 ca = *reinterpret_cast<const float4*>(&sb[d][k0]);
            float4 cb = *reinterpret_cast<const float4*>(&sb[d][k0 + 4]);
            float uu[8] = {ua.x, ua.y, ua.z, ua.w, ub.x, ub.y, ub.z, ub.w};
            float cc[8] = {ca.x, ca.y, ca.z, ca.w, cb.x, cb.y, cb.z, cb.w};
            #pragma unroll
            for (int r = 0; r < 8; ++r) {
                float xr = (&xv[r].x)[dd];
                #pragma unroll
                for (int k = 0; k < 8; ++k) {
                    float t = fmaf(xr, uu[k], -cc[k]);
                    acc[r][k] = fmaf(t, t, acc[r][k]);
                }
            }
        }
    }

    // ---- write partials (each element written by exactly one thread) ----
    #pragma unroll
    for (int r = 0; r < 8; ++r) {
        float* p = &part[((size_t)ds * TB + b0 + r0 + r) * TK + k0];
        *reinterpret_cast<float4*>(p) =
            make_float4(acc[r][0], acc[r][1], acc[r][2], acc[r][3]);
        *reinterpret_cast<float4*>(p + 4) =
            make_float4(acc[r][4], acc[r][5], acc[r][6], acc[r][7]);
    }
}

// ---------------------------------------------------------------------------
// Finish: sum partials + det partials, log-softmax over k, argmax + dist.
// 4 waves/block, 1 row per wave, lane handles k = 2*lane, 2*lane+1.
// ---------------------------------------------------------------------------
__global__ __launch_bounds__(256) void finish_kernel(
        const float* __restrict__ part, const float* __restrict__ logdet_part,
        float* __restrict__ out) {
    const int lane = threadIdx.x & 63;
    const int wv = threadIdx.x >> 6;
    const int b = blockIdx.x * 4 + wv;
    const int k0 = lane * 2;

    float d0 = 0.f, d1 = 0.f;
    float det0 = 0.f, det1 = 0.f;
    #pragma unroll 4
    for (int s = 0; s < DSPLIT; ++s) {
        float2 p = *reinterpret_cast<const float2*>(
            &part[((size_t)s * TB + b) * TK + k0]);
        d0 += p.x; d1 += p.y;
        float2 dt = *reinterpret_cast<const float2*>(&logdet_part[s * TK + k0]);
        det0 += dt.x; det1 += dt.y;
    }
    float s0 = fmaf(-0.5f, d0, det0);
    float s1 = fmaf(-0.5f, d1, det1);

    float m = fmaxf(s0, s1);
    #pragma unroll
    for (int msk = 32; msk >= 1; msk >>= 1) m = fmaxf(m, __shfl_xor(m, msk, 64));
    float p0 = expf(s0 - m), p1 = expf(s1 - m);
    float ps = p0 + p1;
    #pragma unroll
    for (int msk = 32; msk >= 1; msk >>= 1) ps += __shfl_xor(ps, msk, 64);
    float lse = logf(ps) + m;

    const float LOGC = -18.420680743952367f;  // ln(1e-8)
    float2 o;
    o.x = fmaxf(s0 - lse, LOGC);
    o.y = fmaxf(s1 - lse, LOGC);
    *reinterpret_cast<float2*>(&out[(size_t)b * TK + k0]) = o;

    // Argmax over s (first index on ties), carrying dist_sq.
    float bv; int bi; float bd;
    if (s1 > s0) { bv = s1; bi = k0 + 1; bd = d1; }
    else         { bv = s0; bi = k0;     bd = d0; }
    #pragma unroll
    for (int msk = 32; msk >= 1; msk >>= 1) {
        float ov = __shfl_xor(bv, msk, 64);
        int   oi = __shfl_xor(bi, msk, 64);
        float od = __shfl_xor(bd, msk, 64);
        if (ov > bv || (ov == bv && oi < bi)) { bv = ov; bi = oi; bd = od; }
    }
    if (lane == 0) out[(size_t)TB * TK + b] = sqrtf(bd);
}

// ---------------------------------------------------------------------------
extern "C" void kernel_launch(void* const* d_in, const int* in_sizes, int n_in,
                              void* d_out, int out_size, void* d_ws, size_t ws_size,
                              hipStream_t stream) {
    const float* x  = (const float*)d_in[0];
    const float* C  = (const float*)d_in[1];
    const float* Dm = (const float*)d_in[2];
    float* out = (float*)d_out;

    float* part        = (float*)d_ws;                          // 16 MB
    float* logdet_part = (float*)((char*)d_ws + (16ull << 20)); // 8 KB

    dist_kernel<<<NRB * DSPLIT, 128, 0, stream>>>(x, C, Dm, part, logdet_part);
    finish_kernel<<<TB / 4, 256, 0, stream>>>(part, logdet_part, out);
}

// Round 6
// 29.645 us; speedup vs baseline: 7.8335x; 1.0195x over previous
//
#include <hip/hip_runtime.h>
#include <math.h>

#define TB 2048
#define TK 128
#define TD 512
#define DSPLIT 16
#define DLEN 32            // TD / DSPLIT
#define BROWS 64
#define NRB (TB / BROWS)   // 32

// ws layout: [0, 16MB) part[ds][b][k] ; [16MB, +8KB) logdet_part[ds][k]

// ---------------------------------------------------------------------------
// dist kernel: block = 64 rows x 128 k x 32 d slice; 128 threads (2 waves).
// Thread tile = 8 rows x 8 k. One-shot LDS staging, one barrier, pure FMA.
// Inner loop written SROA-safe: plain float acc[8][8] with constant indices,
// scalar x broadcast reads, explicit float4 component use. No local arrays
// built from vector extracts, no address-of vector members.
// ---------------------------------------------------------------------------
__global__ __launch_bounds__(128) void dist_kernel(
        const float* __restrict__ x, const float* __restrict__ C,
        const float* __restrict__ Dm, float* __restrict__ part,
        float* __restrict__ logdet_part) {
    __shared__ float sa[DLEN][TK];    // 16 KB : u = rsqrt(|D|+eps), [d][k]
    __shared__ float sb[DLEN][TK];    // 16 KB : c*u, [d][k]
    __shared__ float xs[BROWS][DLEN]; //  8 KB : x tile, [row][d]

    const int tid = threadIdx.x;
    const int rb = blockIdx.x / DSPLIT;
    const int ds = blockIdx.x % DSPLIT;
    const int b0 = rb * BROWS;
    const int d0 = ds * DLEN;

    // ---- stage x tile: 64 rows x 32 d = 512 float4, 4 per thread ----
    #pragma unroll
    for (int i = 0; i < 4; ++i) {
        int f = i * 128 + tid;        // 0..511
        int row = f >> 3;             // 0..63
        int j = f & 7;                // f4 index within row slice
        float4 v = *reinterpret_cast<const float4*>(
            &x[(size_t)(b0 + row) * TD + d0 + j * 4]);
        *reinterpret_cast<float4*>(&xs[row][j * 4]) = v;
    }

    // ---- stage params: 128 k x 8 f4 = 1024 f4, 8 per thread (coalesced) ----
    #pragma unroll
    for (int i = 0; i < 8; ++i) {
        int f = i * 128 + tid;        // 0..1023
        int k = f >> 3;               // 0..127
        int j = f & 7;
        float4 dv = *reinterpret_cast<const float4*>(&Dm[(size_t)k * TD + d0 + j * 4]);
        float4 cv = *reinterpret_cast<const float4*>(&C[(size_t)k * TD + d0 + j * 4]);
        float da0 = fabsf(dv.x) + 1e-8f, u0 = rsqrtf(da0);
        float da1 = fabsf(dv.y) + 1e-8f, u1 = rsqrtf(da1);
        float da2 = fabsf(dv.z) + 1e-8f, u2 = rsqrtf(da2);
        float da3 = fabsf(dv.w) + 1e-8f, u3 = rsqrtf(da3);
        int db = j * 4;
        sa[db + 0][k] = u0; sb[db + 0][k] = cv.x * u0;
        sa[db + 1][k] = u1; sb[db + 1][k] = cv.y * u1;
        sa[db + 2][k] = u2; sb[db + 2][k] = cv.z * u2;
        sa[db + 3][k] = u3; sb[db + 3][k] = cv.w * u3;
        if (rb == 0) {
            float ls = logf(da0) + logf(da1) + logf(da2) + logf(da3);
            ls += __shfl_xor(ls, 1, 64);
            ls += __shfl_xor(ls, 2, 64);
            ls += __shfl_xor(ls, 4, 64);
            if ((tid & 7) == 0) logdet_part[ds * TK + k] = -0.5f * ls;
        }
    }
    __syncthreads();

    const int k0 = (tid & 15) * 8;
    const int r0 = (tid >> 4) * 8;

    float acc[8][8];
    #pragma unroll
    for (int r = 0; r < 8; ++r)
        #pragma unroll
        for (int k = 0; k < 8; ++k) acc[r][k] = 0.f;

    #pragma unroll
    for (int d = 0; d < DLEN; ++d) {
        const float4 ua = *reinterpret_cast<const float4*>(&sa[d][k0]);
        const float4 ub = *reinterpret_cast<const float4*>(&sa[d][k0 + 4]);
        const float4 ca = *reinterpret_cast<const float4*>(&sb[d][k0]);
        const float4 cb = *reinterpret_cast<const float4*>(&sb[d][k0 + 4]);
        #pragma unroll
        for (int r = 0; r < 8; ++r) {
            const float xr = xs[r0 + r][d];   // broadcast among 16 lanes
            float t;
            t = fmaf(xr, ua.x, -ca.x); acc[r][0] = fmaf(t, t, acc[r][0]);
            t = fmaf(xr, ua.y, -ca.y); acc[r][1] = fmaf(t, t, acc[r][1]);
            t = fmaf(xr, ua.z, -ca.z); acc[r][2] = fmaf(t, t, acc[r][2]);
            t = fmaf(xr, ua.w, -ca.w); acc[r][3] = fmaf(t, t, acc[r][3]);
            t = fmaf(xr, ub.x, -cb.x); acc[r][4] = fmaf(t, t, acc[r][4]);
            t = fmaf(xr, ub.y, -cb.y); acc[r][5] = fmaf(t, t, acc[r][5]);
            t = fmaf(xr, ub.z, -cb.z); acc[r][6] = fmaf(t, t, acc[r][6]);
            t = fmaf(xr, ub.w, -cb.w); acc[r][7] = fmaf(t, t, acc[r][7]);
        }
    }

    // ---- write partials (each element written by exactly one thread) ----
    #pragma unroll
    for (int r = 0; r < 8; ++r) {
        float* p = &part[((size_t)ds * TB + b0 + r0 + r) * TK + k0];
        *reinterpret_cast<float4*>(p) =
            make_float4(acc[r][0], acc[r][1], acc[r][2], acc[r][3]);
        *reinterpret_cast<float4*>(p + 4) =
            make_float4(acc[r][4], acc[r][5], acc[r][6], acc[r][7]);
    }
}

// ---------------------------------------------------------------------------
// Finish: sum partials + det partials, log-softmax over k, argmax + dist.
// 4 waves/block, 1 row per wave, lane handles k = 2*lane, 2*lane+1.
// ---------------------------------------------------------------------------
__global__ __launch_bounds__(256) void finish_kernel(
        const float* __restrict__ part, const float* __restrict__ logdet_part,
        float* __restrict__ out) {
    const int lane = threadIdx.x & 63;
    const int wv = threadIdx.x >> 6;
    const int b = blockIdx.x * 4 + wv;
    const int k0 = lane * 2;

    float d0 = 0.f, d1 = 0.f;
    float det0 = 0.f, det1 = 0.f;
    #pragma unroll 4
    for (int s = 0; s < DSPLIT; ++s) {
        float2 p = *reinterpret_cast<const float2*>(
            &part[((size_t)s * TB + b) * TK + k0]);
        d0 += p.x; d1 += p.y;
        float2 dt = *reinterpret_cast<const float2*>(&logdet_part[s * TK + k0]);
        det0 += dt.x; det1 += dt.y;
    }
    float s0 = fmaf(-0.5f, d0, det0);
    float s1 = fmaf(-0.5f, d1, det1);

    float m = fmaxf(s0, s1);
    #pragma unroll
    for (int msk = 32; msk >= 1; msk >>= 1) m = fmaxf(m, __shfl_xor(m, msk, 64));
    float p0 = expf(s0 - m), p1 = expf(s1 - m);
    float ps = p0 + p1;
    #pragma unroll
    for (int msk = 32; msk >= 1; msk >>= 1) ps += __shfl_xor(ps, msk, 64);
    float lse = logf(ps) + m;

    const float LOGC = -18.420680743952367f;  // ln(1e-8)
    float2 o;
    o.x = fmaxf(s0 - lse, LOGC);
    o.y = fmaxf(s1 - lse, LOGC);
    *reinterpret_cast<float2*>(&out[(size_t)b * TK + k0]) = o;

    // Argmax over s (first index on ties), carrying dist_sq.
    float bv; int bi; float bd;
    if (s1 > s0) { bv = s1; bi = k0 + 1; bd = d1; }
    else         { bv = s0; bi = k0;     bd = d0; }
    #pragma unroll
    for (int msk = 32; msk >= 1; msk >>= 1) {
        float ov = __shfl_xor(bv, msk, 64);
        int   oi = __shfl_xor(bi, msk, 64);
        float od = __shfl_xor(bd, msk, 64);
        if (ov > bv || (ov == bv && oi < bi)) { bv = ov; bi = oi; bd = od; }
    }
    if (lane == 0) out[(size_t)TB * TK + b] = sqrtf(bd);
}

// ---------------------------------------------------------------------------
extern "C" void kernel_launch(void* const* d_in, const int* in_sizes, int n_in,
                              void* d_out, int out_size, void* d_ws, size_t ws_size,
                              hipStream_t stream) {
    const float* x  = (const float*)d_in[0];
    const float* C  = (const float*)d_in[1];
    const float* Dm = (const float*)d_in[2];
    float* out = (float*)d_out;

    float* part        = (float*)d_ws;                          // 16 MB
    float* logdet_part = (float*)((char*)d_ws + (16ull << 20)); // 8 KB

    dist_kernel<<<NRB * DSPLIT, 128, 0, stream>>>(x, C, Dm, part, logdet_part);
    finish_kernel<<<TB / 4, 256, 0, stream>>>(part, logdet_part, out);
}